// Round 1
// baseline (943.135 us; speedup 1.0000x reference)
//
#include <hip/hip_runtime.h>
#include <stdint.h>

// ---------------------------------------------------------------------------
// MS_SSA_Conv: spiking self-attention. T=4 B=8 C=384 N=1024 heads=8.
// R4 changes vs R3:
//  * qkv: t folded into the tile (128o x 512col = 4t x 128n), LIF over t done
//    in the epilogue from accumulators -> 24 K-stages staged ONCE (was 48).
//    BK=32 dbuf = 80KB LDS -> 2 blocks/CU (16 waves/CU, was 8).
//    Counted vmcnt(5) pipeline: fused "s_waitcnt vmcnt(5); s_barrier" inline
//    asm (no __syncthreads drain), stage(s+2) issued before MFMA cluster,
//    setprio(1) around MFMAs. Wave-tile 64x128 (42.7 FLOP/LDS-byte, was 32).
// ---------------------------------------------------------------------------

typedef unsigned short u16;
typedef __attribute__((ext_vector_type(8))) short short8v;
typedef __attribute__((ext_vector_type(4))) float f32x4;

#define AS1 __attribute__((address_space(1)))
#define AS3 __attribute__((address_space(3)))

__device__ __forceinline__ void async16(const void* g, void* l) {
    __builtin_amdgcn_global_load_lds((const AS1 unsigned int*)g,
                                     (AS3 unsigned int*)l, 16, 0, 0);
}
__device__ __forceinline__ f32x4 mfma_bf16(short8v a, short8v b, f32x4 c) {
    return __builtin_amdgcn_mfma_f32_16x16x32_bf16(a, b, c, 0, 0, 0);
}
__device__ __forceinline__ f32x4 mfma_f16(short8v a, short8v b, f32x4 c) {
    return __builtin_amdgcn_mfma_f32_16x16x32_f16(a, b, c, 0, 0, 0);
}

__device__ __forceinline__ u16 f2bf(float f) {  // RNE fp32->bf16
    uint32_t x = __float_as_uint(f);
    return (u16)((x + 0x7FFFu + ((x >> 16) & 1u)) >> 16);
}

#define SPIKE_H ((u16)0x3C00)  // fp16 1.0 (xs)
#define SPIKE_B ((u16)0x3F80)  // bf16 1.0 (q/k/v spikes, kvs mask)

// ---------------------------------------------------------------------------
// K0: weights. Ah [1152][768] fp16 2-part split (part-major cols);
// Aproj [384][384] bf16.
// ---------------------------------------------------------------------------
__global__ void prep_kernel(const float* __restrict__ qw, const float* __restrict__ kw,
                            const float* __restrict__ vw, const float* __restrict__ pw,
                            u16* __restrict__ Ah, u16* __restrict__ Aproj) {
    int id = blockIdx.x * 256 + threadIdx.x;
    if (id >= 1152 * 384) return;
    int m = id / 384, c = id % 384;
    int br = m / 384, o = m % 384;
    const float* W = (br == 0) ? qw : (br == 1) ? kw : vw;
    float w = W[o * 384 + c];
    union H { _Float16 h; u16 u; } u0, u1;
    u0.h = (_Float16)w;
    float r1 = w - (float)u0.h;
    u1.h = (_Float16)r1;
    u16* row = Ah + (size_t)m * 768;
    row[c] = u0.u;
    row[384 + c] = u1.u;
    if (br == 0) Aproj[o * 384 + c] = f2bf(pw[o * 384 + c]);
}

// ---------------------------------------------------------------------------
// K1: shortcut LIF on x -> xs[t,b,n,c] fp16 spikes.
// ---------------------------------------------------------------------------
__global__ __launch_bounds__(256) void lifx_kernel(const float* __restrict__ x,
                                                   u16* __restrict__ xs) {
    __shared__ u16 Tr[64 * 72];
    int b = blockIdx.z, c0 = blockIdx.y * 64, n0 = blockIdx.x * 64;
    int tid = threadIdx.x;
    int nj = (tid & 15) * 4;
    int ci = tid >> 4;
    float v[4][4];
#pragma unroll
    for (int p = 0; p < 4; p++)
#pragma unroll
        for (int e = 0; e < 4; e++) v[p][e] = 0.0f;

    for (int t = 0; t < 4; t++) {
#pragma unroll
        for (int p = 0; p < 4; p++) {
            const float* src = x + ((size_t)((t * 8 + b) * 384 + c0 + p * 16 + ci)) * 1024 + n0 + nj;
            float4 xv = *(const float4*)src;
            float xa[4] = {xv.x, xv.y, xv.z, xv.w};
#pragma unroll
            for (int e = 0; e < 4; e++) {
                float vv = v[p][e];
                vv = __fadd_rn(vv, __fmul_rn(__fsub_rn(xa[e], vv), 0.5f));
                bool sp = (vv >= 0.5f);
                v[p][e] = sp ? 0.0f : vv;
                Tr[(nj + e) * 72 + p * 16 + ci] = sp ? SPIKE_H : (u16)0;
            }
        }
        __syncthreads();
#pragma unroll
        for (int p = 0; p < 4; p++) {
            int nr = p * 16 + (tid >> 4);
            int c4 = (tid & 15) * 4;
            *(ushort4*)(xs + ((size_t)((t * 8 + b) * 1024 + n0 + nr)) * 384 + c0 + c4) =
                *(const ushort4*)&Tr[nr * 72 + c4];
        }
        __syncthreads();
    }
}

// ---------------------------------------------------------------------------
// K2: QKV conv (2-part fp16, K=768) + BN + LIF.
// Tile: 128 o x 512 cols (4t x 128n), all 4 t in acc -> LIF in epilogue.
// 8 waves (2 o-waves x 4 n-groups), wave-tile 64 x 128. BK=32, 2-buf LDS
// (80KB exactly -> 2 blocks/CU). Counted-vmcnt pipeline, raw s_barrier.
// grid (nt=8, mt=9, b=8), 512 threads.
// ---------------------------------------------------------------------------
__global__ __launch_bounds__(512, 4) void qkv_kernel(
    const u16* __restrict__ Ah, const u16* __restrict__ xs,
    u16* __restrict__ qs, u16* __restrict__ ks, u16* __restrict__ vs,
    const float* __restrict__ qg, const float* __restrict__ qb, const float* __restrict__ qm, const float* __restrict__ qv,
    const float* __restrict__ kg, const float* __restrict__ kb, const float* __restrict__ km, const float* __restrict__ kvr,
    const float* __restrict__ vg, const float* __restrict__ vb, const float* __restrict__ vm, const float* __restrict__ vvr) {
    __shared__ __align__(16) u16 At[2][4096];   // [buf][row(128) * 32k]  16 KB
    __shared__ __align__(16) u16 Bt[2][16384];  // [buf][col(512) * 32k]  64 KB

    int b = blockIdx.z, mt = blockIdx.y, nt = blockIdx.x;
    int m0 = mt * 128, n0 = nt * 128;
    int branch = mt / 3, o0 = (mt % 3) * 128;
    int tid = threadIdx.x, wave = tid >> 6, lane = tid & 63;
    int l15 = lane & 15, quad = lane >> 4;
    int wm = (wave & 1) * 64;  // o-offset of wave within 128
    int wc = wave >> 1;        // n-group 0..3 (32 n each)

    // per-thread staging sources (chunk pre-swizzled so linear LDS dest +
    // swizzled read are the same involution; 4 chunks of 16B per 64B row)
    int arow = tid >> 2;
    const u16* asrc = Ah + (size_t)(m0 + arow) * 768 + ((tid & 3) ^ (arow & 3)) * 8;
    const u16* bsrc[4];
#pragma unroll
    for (int ii = 0; ii < 4; ii++) {
        int l = ii * 512 + tid;
        int col = l >> 2;                    // 0..511 = t*128 + nl
        int cs = (l & 3) ^ (col & 3);
        int t = col >> 7, nl = col & 127;
        bsrc[ii] = xs + ((size_t)((t * 8 + b) * 1024 + n0 + nl)) * 384 + cs * 8;
    }

    // stage s (K-chunk of 32): 1 A-load + 4 B-loads per thread (vmcnt unit = 5)
    auto stage = [&](int s) {
        int buf = s & 1;
        int kk = s * 32;
        int ck = (kk >= 384) ? (kk - 384) : kk;  // 2-part split: B repeats
        async16(asrc + kk, &At[buf][tid * 8]);
#pragma unroll
        for (int ii = 0; ii < 4; ii++)
            async16(bsrc[ii] + ck, &Bt[buf][(ii * 512 + tid) * 8]);
    };

    // fragment LDS offsets (u16 units), swizzled chunk = quad ^ (row&3)
    int aoff[4], boff[8];
#pragma unroll
    for (int i = 0; i < 4; i++) {
        int row = wm + i * 16 + l15;
        aoff[i] = row * 32 + (quad ^ (row & 3)) * 8;
    }
#pragma unroll
    for (int j = 0; j < 8; j++) {  // j = t*2 + h: col = t*128 + wc*32 + h*16 + l15
        int col = (j >> 1) * 128 + wc * 32 + (j & 1) * 16 + l15;
        boff[j] = col * 32 + (quad ^ (col & 3)) * 8;
    }

    f32x4 acc[4][8];
#pragma unroll
    for (int i = 0; i < 4; i++)
#pragma unroll
        for (int j = 0; j < 8; j++) acc[i][j] = (f32x4){0.f, 0.f, 0.f, 0.f};

    stage(0);
    stage(1);

#pragma unroll 1
    for (int s = 0; s < 24; ++s) {
        int buf = s & 1;
        // wait own stage-s loads (5 newest = stage s+1 may stay in flight),
        // then barrier: all waves' stage-s loads landed. Fused asm so the
        // compiler cannot insert a vmcnt(0) drain.
        if (s < 23) asm volatile("s_waitcnt vmcnt(5)\n\ts_barrier" ::: "memory");
        else        asm volatile("s_waitcnt vmcnt(0)\n\ts_barrier" ::: "memory");

        short8v af[4], bf[8];
#pragma unroll
        for (int i = 0; i < 4; i++) af[i] = *(const short8v*)&At[buf][aoff[i]];
#pragma unroll
        for (int j = 0; j < 8; j++) bf[j] = *(const short8v*)&Bt[buf][boff[j]];

        // reads complete before anyone overwrites this buffer (stage s+2)
        asm volatile("s_waitcnt lgkmcnt(0)\n\ts_barrier" ::: "memory");
        if (s + 2 < 24) stage(s + 2);  // issue next loads BEFORE MFMA cluster

        __builtin_amdgcn_s_setprio(1);
#pragma unroll
        for (int i = 0; i < 4; i++)
#pragma unroll
            for (int j = 0; j < 8; j++) acc[i][j] = mfma_f16(af[i], bf[j], acc[i][j]);
        __builtin_amdgcn_s_setprio(0);
    }

    // epilogue: BN + LIF over t (exact numpy order) from accumulators
    const float* g_  = (branch == 0) ? qg : (branch == 1) ? kg : vg;
    const float* be_ = (branch == 0) ? qb : (branch == 1) ? kb : vb;
    const float* m_  = (branch == 0) ? qm : (branch == 1) ? km : vm;
    const float* v_  = (branch == 0) ? qv : (branch == 1) ? kvr : vvr;
    u16* dstp = (branch == 0) ? qs : (branch == 1) ? ks : vs;

#pragma unroll
    for (int i = 0; i < 4; i++) {
        int co = wm + i * 16 + quad * 4;
        int o = o0 + co;
        float4 g4  = *(const float4*)&g_[o];
        float4 va4 = *(const float4*)&v_[o];
        float4 mn4 = *(const float4*)&m_[o];
        float4 be4 = *(const float4*)&be_[o];
        float sc[4] = {g4.x / sqrtf(va4.x + 1e-5f), g4.y / sqrtf(va4.y + 1e-5f),
                       g4.z / sqrtf(va4.z + 1e-5f), g4.w / sqrtf(va4.w + 1e-5f)};
        float mn[4] = {mn4.x, mn4.y, mn4.z, mn4.w};
        float bt[4] = {be4.x, be4.y, be4.z, be4.w};
#pragma unroll
        for (int h = 0; h < 2; h++) {
            int n = n0 + wc * 32 + h * 16 + l15;
            u16 sv[4][4];  // [t][e]
#pragma unroll
            for (int e = 0; e < 4; e++) {
                float vv = 0.0f;
#pragma unroll
                for (int t = 0; t < 4; t++) {
                    float a = acc[i][t * 2 + h][e];
                    a = __fadd_rn(__fmul_rn(__fsub_rn(a, mn[e]), sc[e]), bt[e]);
                    vv = __fadd_rn(vv, __fmul_rn(__fsub_rn(a, vv), 0.5f));
                    bool sp = (vv >= 0.5f);
                    vv = sp ? 0.0f : vv;
                    sv[t][e] = sp ? SPIKE_B : (u16)0;
                }
            }
#pragma unroll
            for (int t = 0; t < 4; t++) {
                ushort4 s4;
                s4.x = sv[t][0]; s4.y = sv[t][1]; s4.z = sv[t][2]; s4.w = sv[t][3];
                *(ushort4*)(dstp + ((size_t)((t * 8 + b) * 1024 + n)) * 384 + o) = s4;
            }
        }
    }
}

// ---------------------------------------------------------------------------
// K3: kv[t,b,c] = sum_n k*v. 16B loads, 8 ch/thread, LDS pre-reduce.
// grid (nc=16, tb=32), 384 thr: tid = rr*48 + c8.
// ---------------------------------------------------------------------------
__global__ void kvred_kernel(const u16* __restrict__ ks, const u16* __restrict__ vs,
                             float* __restrict__ r) {
    __shared__ float red[384];
    int tb = blockIdx.y, nc = blockIdx.x;
    int tid = threadIdx.x;
    int rr = tid / 48, c8 = tid % 48;
    red[tid] = 0.0f;
    __syncthreads();

    float cnt[8];
#pragma unroll
    for (int e = 0; e < 8; e++) cnt[e] = 0.0f;

    size_t base = ((size_t)(tb * 1024 + nc * 64 + rr)) * 384 + c8 * 8;
#pragma unroll 2
    for (int it = 0; it < 8; it++) {
        size_t off = base + (size_t)it * 8 * 384;
        uint4 ka = *(const uint4*)(ks + off);
        uint4 va = *(const uint4*)(vs + off);
        uint32_t w0 = ka.x & va.x, w1 = ka.y & va.y, w2 = ka.z & va.z, w3 = ka.w & va.w;
        const uint32_t S = SPIKE_B;
        if ((w0 & 0xFFFFu) == S) cnt[0] += 1.0f;
        if ((w0 >> 16) == S)     cnt[1] += 1.0f;
        if ((w1 & 0xFFFFu) == S) cnt[2] += 1.0f;
        if ((w1 >> 16) == S)     cnt[3] += 1.0f;
        if ((w2 & 0xFFFFu) == S) cnt[4] += 1.0f;
        if ((w2 >> 16) == S)     cnt[5] += 1.0f;
        if ((w3 & 0xFFFFu) == S) cnt[6] += 1.0f;
        if ((w3 >> 16) == S)     cnt[7] += 1.0f;
    }
#pragma unroll
    for (int e = 0; e < 8; e++) atomicAdd(&red[c8 * 8 + e], cnt[e]);
    __syncthreads();
    atomicAdd(&r[tb * 384 + tid], red[tid]);
}

// K4: talking heads (8x8 fp32) + LIF over t -> kvs[t,b,c] bf16 {0,1} mask
__global__ void talking_kernel(const float* __restrict__ r, const float* __restrict__ th,
                               u16* __restrict__ kvs) {
    int id = blockIdx.x * 256 + threadIdx.x;
    if (id >= 8 * 384) return;
    int b = id / 384, c = id % 384;
    int oh = c / 48, d = c % 48;
    float v = 0.0f;
    for (int t = 0; t < 4; t++) {
        const float* rr = r + (t * 8 + b) * 384 + d;
        float s = 0.0f;
#pragma unroll
        for (int h = 0; h < 8; h++) s = __fmaf_rn(th[oh * 8 + h], rr[h * 48], s);
        v = __fadd_rn(v, __fmul_rn(__fsub_rn(s, v), 0.5f));
        bool sp = (v >= 0.5f);
        v = sp ? 0.0f : v;
        kvs[(t * 8 + b) * 384 + c] = sp ? SPIKE_B : (u16)0;
    }
}

// ---------------------------------------------------------------------------
// K5: proj conv (K=384 bf16) + fused kvs gate + bias + BN + residual.
// 128x128 tiles, dbuf LDS, grid (nt=8, mt=3, tb=32).
// ---------------------------------------------------------------------------
__global__ __launch_bounds__(256, 2) void proj_kernel(
    const u16* __restrict__ Aproj, const u16* __restrict__ qs, const u16* __restrict__ kvs,
    const float* __restrict__ xin,
    const float* __restrict__ pb, const float* __restrict__ pg, const float* __restrict__ pbe,
    const float* __restrict__ pm, const float* __restrict__ pv, float* __restrict__ out) {
    __shared__ __align__(16) u16 At[2][8192];
    __shared__ __align__(16) u16 Bt[2][8192];

    int tb = blockIdx.z, mt = blockIdx.y, nt = blockIdx.x;
    int m0 = mt * 128, n0 = nt * 128;
    int tid = threadIdx.x, wave = tid >> 6, lane = tid & 63;
    int l15 = lane & 15, quad = lane >> 4;
    int wm = (wave & 1) * 64, wn = (wave >> 1) * 64;

    const u16* Bsrc = qs + ((size_t)(tb * 1024 + n0)) * 384;
    const u16* mbase = kvs + tb * 384;

    auto stage = [&](int s) {
        int kk = s * 64;
        int buf = s & 1;
#pragma unroll
        for (int ii = 0; ii < 4; ii++) {
            int l = ii * 256 + tid;
            int row = l >> 3;
            int cs = (l & 7) ^ (row & 7);
            async16(Aproj + (size_t)(m0 + row) * 384 + kk + cs * 8, &At[buf][l * 8]);
            async16(Bsrc + (size_t)row * 384 + kk + cs * 8, &Bt[buf][l * 8]);
        }
    };

    f32x4 acc[4][4];
#pragma unroll
    for (int i = 0; i < 4; i++)
#pragma unroll
        for (int j = 0; j < 4; j++) acc[i][j] = (f32x4){0.f, 0.f, 0.f, 0.f};

    stage(0);
    __syncthreads();

    for (int kkb = 0; kkb < 6; kkb++) {
        int buf = kkb & 1;
        int kk = kkb * 64;
        if (kkb + 1 < 6) stage(kkb + 1);
#pragma unroll
        for (int h = 0; h < 2; h++) {
            int g = h * 4 + quad;
            short8v msk = *(const short8v*)(mbase + kk + g * 8);
            short8v af[4], bfr[4];
#pragma unroll
            for (int i = 0; i < 4; i++) {
                int row = wm + i * 16 + l15;
                int ch = g ^ (row & 7);
                af[i] = *(const short8v*)&At[buf][row * 64 + ch * 8];
            }
#pragma unroll
            for (int j = 0; j < 4; j++) {
                int nr = wn + j * 16 + l15;
                int ch = g ^ (nr & 7);
                bfr[j] = *(const short8v*)&Bt[buf][nr * 64 + ch * 8] & msk;  // gate
            }
#pragma unroll
            for (int i = 0; i < 4; i++)
#pragma unroll
                for (int j = 0; j < 4; j++) acc[i][j] = mfma_bf16(af[i], bfr[j], acc[i][j]);
        }
        __syncthreads();
    }

    // epilogue: y = conv+bias; (y-mean)*scale+beta; + identity (numpy order)
#pragma unroll
    for (int i = 0; i < 4; i++) {
#pragma unroll
        for (int e = 0; e < 4; e++) {
            int o = m0 + wm + i * 16 + quad * 4 + e;
            float scale = pg[o] / sqrtf(pv[o] + 1e-5f);
            float mean = pm[o], beta = pbe[o], bias = pb[o];
#pragma unroll
            for (int j = 0; j < 4; j++) {
                int n = n0 + wn + j * 16 + l15;
                size_t idx = ((size_t)tb * 384 + o) * 1024 + n;
                float y = __fadd_rn(acc[i][j][e], bias);
                y = __fadd_rn(__fmul_rn(__fsub_rn(y, mean), scale), beta);
                out[idx] = __fadd_rn(y, xin[idx]);
            }
        }
    }
}

// ---------------------------------------------------------------------------
extern "C" void kernel_launch(void* const* d_in, const int* in_sizes, int n_in,
                              void* d_out, int out_size, void* d_ws, size_t ws_size,
                              hipStream_t stream) {
    (void)in_sizes; (void)n_in; (void)out_size; (void)ws_size;
    const float* x  = (const float*)d_in[0];
    const float* qw = (const float*)d_in[1];
    const float* kw = (const float*)d_in[2];
    const float* vw = (const float*)d_in[3];
    const float* th = (const float*)d_in[4];
    const float* pw = (const float*)d_in[5];
    const float* pb = (const float*)d_in[6];
    const float* qg = (const float*)d_in[7],  *qbe = (const float*)d_in[8];
    const float* qm = (const float*)d_in[9],  *qv  = (const float*)d_in[10];
    const float* kg = (const float*)d_in[11], *kbe = (const float*)d_in[12];
    const float* km = (const float*)d_in[13], *kv_ = (const float*)d_in[14];
    const float* vg = (const float*)d_in[15], *vbe = (const float*)d_in[16];
    const float* vm = (const float*)d_in[17], *vv_ = (const float*)d_in[18];
    const float* pg = (const float*)d_in[19], *pbe = (const float*)d_in[20];
    const float* pm = (const float*)d_in[21], *pv  = (const float*)d_in[22];
    float* out = (float*)d_out;

    char* w = (char*)d_ws;
    const size_t SPIKES = (size_t)32 * 1024 * 384 * 2;  // 25,165,824 B each
    u16* xs    = (u16*)(w);
    u16* qs    = (u16*)(w + SPIKES);
    u16* ks    = (u16*)(w + 2 * SPIKES);
    u16* vs    = (u16*)(w + 3 * SPIKES);
    u16* Ah    = (u16*)(w + 4 * SPIKES);                         // 1,769,472 B
    u16* Aproj = (u16*)(w + 4 * SPIKES + 1769472);               //   294,912 B
    float* r   = (float*)(w + 4 * SPIKES + 1769472 + 294912);    //    49,152 B
    u16* kvs   = (u16*)(w + 4 * SPIKES + 1769472 + 294912 + 49152);  // 24,576 B

    hipMemsetAsync(r, 0, 32 * 384 * sizeof(float), stream);

    prep_kernel<<<1728, 256, 0, stream>>>(qw, kw, vw, pw, Ah, Aproj);
    lifx_kernel<<<dim3(16, 6, 8), 256, 0, stream>>>(x, xs);
    qkv_kernel<<<dim3(8, 9, 8), 512, 0, stream>>>(Ah, xs, qs, ks, vs,
                                                  qg, qbe, qm, qv,
                                                  kg, kbe, km, kv_,
                                                  vg, vbe, vm, vv_);
    kvred_kernel<<<dim3(16, 32), 384, 0, stream>>>(ks, vs, r);
    talking_kernel<<<12, 256, 0, stream>>>(r, th, kvs);
    proj_kernel<<<dim3(8, 3, 32), 256, 0, stream>>>(Aproj, qs, kvs, x, pb, pg, pbe, pm, pv, out);
}

// Round 2
// 294.268 us; speedup vs baseline: 3.2050x; 3.2050x over previous
//
#include <hip/hip_runtime.h>
#include <stdint.h>

// ---------------------------------------------------------------------------
// MS_SSA_Conv: spiking self-attention. T=4 B=8 C=384 N=1024 heads=8.
// R5 = R3 structure (verified: 0 bank conflicts, VGPR=104, no spills)
//      + counted-vmcnt pipeline in qkv/proj K-loops:
//   * per stage: "s_waitcnt vmcnt(8); s_barrier" (stage s+1 stays in flight,
//     never drain to 0 in main loop) -> frag reads -> "lgkmcnt(0); s_barrier"
//     -> stage(s+2) prefetch -> MFMA cluster in s_setprio(1).
//   * R4 lesson: do NOT raise launch_bounds min-waves (VGPR cap -> spills),
//     do NOT shrink LDS rows below 128B (breaks the measured-conflict-free
//     swizzle).
// ---------------------------------------------------------------------------

typedef unsigned short u16;
typedef __attribute__((ext_vector_type(8))) short short8v;
typedef __attribute__((ext_vector_type(4))) float f32x4;

#define AS1 __attribute__((address_space(1)))
#define AS3 __attribute__((address_space(3)))

__device__ __forceinline__ void async16(const void* g, void* l) {
    __builtin_amdgcn_global_load_lds((const AS1 unsigned int*)g,
                                     (AS3 unsigned int*)l, 16, 0, 0);
}
__device__ __forceinline__ f32x4 mfma_bf16(short8v a, short8v b, f32x4 c) {
    return __builtin_amdgcn_mfma_f32_16x16x32_bf16(a, b, c, 0, 0, 0);
}
__device__ __forceinline__ f32x4 mfma_f16(short8v a, short8v b, f32x4 c) {
    return __builtin_amdgcn_mfma_f32_16x16x32_f16(a, b, c, 0, 0, 0);
}

__device__ __forceinline__ u16 f2bf(float f) {  // RNE fp32->bf16
    uint32_t x = __float_as_uint(f);
    return (u16)((x + 0x7FFFu + ((x >> 16) & 1u)) >> 16);
}

#define SPIKE_H ((u16)0x3C00)  // fp16 1.0 (xs)
#define SPIKE_B ((u16)0x3F80)  // bf16 1.0 (q/k/v spikes, kvs mask)

// ---------------------------------------------------------------------------
// K0: weights. Ah [1152][768] fp16 2-part split (part-major cols);
// Aproj [384][384] bf16.
// ---------------------------------------------------------------------------
__global__ void prep_kernel(const float* __restrict__ qw, const float* __restrict__ kw,
                            const float* __restrict__ vw, const float* __restrict__ pw,
                            u16* __restrict__ Ah, u16* __restrict__ Aproj) {
    int id = blockIdx.x * 256 + threadIdx.x;
    if (id >= 1152 * 384) return;
    int m = id / 384, c = id % 384;
    int br = m / 384, o = m % 384;
    const float* W = (br == 0) ? qw : (br == 1) ? kw : vw;
    float w = W[o * 384 + c];
    union H { _Float16 h; u16 u; } u0, u1;
    u0.h = (_Float16)w;
    float r1 = w - (float)u0.h;
    u1.h = (_Float16)r1;
    u16* row = Ah + (size_t)m * 768;
    row[c] = u0.u;
    row[384 + c] = u1.u;
    if (br == 0) Aproj[o * 384 + c] = f2bf(pw[o * 384 + c]);
}

// ---------------------------------------------------------------------------
// K1: shortcut LIF on x -> xs[t,b,n,c] fp16 spikes.
// ---------------------------------------------------------------------------
__global__ __launch_bounds__(256) void lifx_kernel(const float* __restrict__ x,
                                                   u16* __restrict__ xs) {
    __shared__ u16 Tr[64 * 72];
    int b = blockIdx.z, c0 = blockIdx.y * 64, n0 = blockIdx.x * 64;
    int tid = threadIdx.x;
    int nj = (tid & 15) * 4;
    int ci = tid >> 4;
    float v[4][4];
#pragma unroll
    for (int p = 0; p < 4; p++)
#pragma unroll
        for (int e = 0; e < 4; e++) v[p][e] = 0.0f;

    for (int t = 0; t < 4; t++) {
#pragma unroll
        for (int p = 0; p < 4; p++) {
            const float* src = x + ((size_t)((t * 8 + b) * 384 + c0 + p * 16 + ci)) * 1024 + n0 + nj;
            float4 xv = *(const float4*)src;
            float xa[4] = {xv.x, xv.y, xv.z, xv.w};
#pragma unroll
            for (int e = 0; e < 4; e++) {
                float vv = v[p][e];
                vv = __fadd_rn(vv, __fmul_rn(__fsub_rn(xa[e], vv), 0.5f));
                bool sp = (vv >= 0.5f);
                v[p][e] = sp ? 0.0f : vv;
                Tr[(nj + e) * 72 + p * 16 + ci] = sp ? SPIKE_H : (u16)0;
            }
        }
        __syncthreads();
#pragma unroll
        for (int p = 0; p < 4; p++) {
            int nr = p * 16 + (tid >> 4);
            int c4 = (tid & 15) * 4;
            *(ushort4*)(xs + ((size_t)((t * 8 + b) * 1024 + n0 + nr)) * 384 + c0 + c4) =
                *(const ushort4*)&Tr[nr * 72 + c4];
        }
        __syncthreads();
    }
}

// ---------------------------------------------------------------------------
// K2: QKV conv (2-part fp16, K=768) + BN + LIF over t, membrane in regs.
// 128x128 tile, dbuf LDS, 48 stages (t-major), counted-vmcnt pipeline:
// never drain vmcnt to 0 in main loop. grid (nt=8, mt=9, b=8), 256 thr.
// ---------------------------------------------------------------------------
__global__ __launch_bounds__(256, 2) void qkv_kernel(
    const u16* __restrict__ Ah, const u16* __restrict__ xs,
    u16* __restrict__ qs, u16* __restrict__ ks, u16* __restrict__ vs,
    const float* __restrict__ qg, const float* __restrict__ qb, const float* __restrict__ qm, const float* __restrict__ qv,
    const float* __restrict__ kg, const float* __restrict__ kb, const float* __restrict__ km, const float* __restrict__ kvr,
    const float* __restrict__ vg, const float* __restrict__ vb, const float* __restrict__ vm, const float* __restrict__ vvr) {
    __shared__ __align__(16) u16 At[2][8192];
    __shared__ __align__(16) u16 Bt[2][8192];
    __shared__ __align__(16) float bnS[128];
    __shared__ __align__(16) float bnM[128];
    __shared__ __align__(16) float bnB[128];

    int b = blockIdx.z, mt = blockIdx.y, nt = blockIdx.x;
    int m0 = mt * 128, n0 = nt * 128;
    int branch = mt / 3, o0 = (mt % 3) * 128;
    int tid = threadIdx.x, wave = tid >> 6, lane = tid & 63;
    int l15 = lane & 15, quad = lane >> 4;
    int wm = (wave & 1) * 64, wn = (wave >> 1) * 64;

    const float* g_ = (branch == 0) ? qg : (branch == 1) ? kg : vg;
    const float* be_ = (branch == 0) ? qb : (branch == 1) ? kb : vb;
    const float* m_ = (branch == 0) ? qm : (branch == 1) ? km : vm;
    const float* v_ = (branch == 0) ? qv : (branch == 1) ? kvr : vvr;
    u16* dstp = (branch == 0) ? qs : (branch == 1) ? ks : vs;

    if (tid < 128) {
        int o = o0 + tid;
        bnS[tid] = g_[o] / sqrtf(v_[o] + 1e-5f);
        bnM[tid] = m_[o];
        bnB[tid] = be_[o];
    }

    // stage s in [0,48): t = s/12, kkb = s%12. Buffer s&1. 8 loads/thread.
    auto stage = [&](int s) {
        int st = s / 12, kkb = s % 12;
        int buf = s & 1;
        int kk = kkb * 64;
        int ck = (kk >= 384) ? kk - 384 : kk;
        const u16* Bsrc = xs + ((size_t)((st * 8 + b) * 1024 + n0)) * 384;
#pragma unroll
        for (int ii = 0; ii < 4; ii++) {
            int l = ii * 256 + tid;
            int row = l >> 3;
            int cs = (l & 7) ^ (row & 7);
            async16(Ah + (size_t)(m0 + row) * 768 + kk + cs * 8, &At[buf][l * 8]);
            async16(Bsrc + (size_t)row * 384 + ck + cs * 8, &Bt[buf][l * 8]);
        }
    };

    float vmem[4][4][4];
#pragma unroll
    for (int i = 0; i < 4; i++)
#pragma unroll
        for (int j = 0; j < 4; j++)
#pragma unroll
            for (int e = 0; e < 4; e++) vmem[i][j][e] = 0.0f;

    stage(0);
    stage(1);

    for (int t = 0; t < 4; t++) {
        f32x4 acc[4][4];
#pragma unroll
        for (int i = 0; i < 4; i++)
#pragma unroll
            for (int j = 0; j < 4; j++) acc[i][j] = (f32x4){0.f, 0.f, 0.f, 0.f};

#pragma unroll 1
        for (int kkb = 0; kkb < 12; kkb++) {
            int s = t * 12 + kkb;
            int buf = s & 1;
            // stage s landed for all waves; stage s+1 may stay in flight
            // (8 loads/thread/stage). Fused asm: compiler cannot add a
            // vmcnt(0) drain.
            if (s < 47) asm volatile("s_waitcnt vmcnt(8)\n\ts_barrier" ::: "memory");
            else        asm volatile("s_waitcnt vmcnt(0)\n\ts_barrier" ::: "memory");

#pragma unroll
            for (int h = 0; h < 2; h++) {
                short8v af[4], bfr[4];
#pragma unroll
                for (int i = 0; i < 4; i++) {
                    int row = wm + i * 16 + l15;
                    int ch = (h * 4 + quad) ^ (row & 7);
                    af[i] = *(const short8v*)&At[buf][row * 64 + ch * 8];
                }
#pragma unroll
                for (int j = 0; j < 4; j++) {
                    int nr = wn + j * 16 + l15;
                    int ch = (h * 4 + quad) ^ (nr & 7);
                    bfr[j] = *(const short8v*)&Bt[buf][nr * 64 + ch * 8];
                }
                __builtin_amdgcn_s_setprio(1);
#pragma unroll
                for (int i = 0; i < 4; i++)
#pragma unroll
                    for (int j = 0; j < 4; j++) acc[i][j] = mfma_f16(af[i], bfr[j], acc[i][j]);
                __builtin_amdgcn_s_setprio(0);
            }

            // all waves done reading buf s -> safe to overwrite with s+2
            asm volatile("s_waitcnt lgkmcnt(0)\n\ts_barrier" ::: "memory");
            if (s + 2 < 48) stage(s + 2);
        }

        // epilogue: BN + LIF (exact numpy order) -> direct ushort4 stores
        size_t rb = (size_t)((t * 8 + b) * 1024 + n0);
#pragma unroll
        for (int i = 0; i < 4; i++) {
            int co = wm + i * 16 + quad * 4;
            float4 sc4 = *(const float4*)&bnS[co];
            float4 mn4 = *(const float4*)&bnM[co];
            float4 bt4 = *(const float4*)&bnB[co];
            float scA[4] = {sc4.x, sc4.y, sc4.z, sc4.w};
            float mnA[4] = {mn4.x, mn4.y, mn4.z, mn4.w};
            float btA[4] = {bt4.x, bt4.y, bt4.z, bt4.w};
#pragma unroll
            for (int j = 0; j < 4; j++) {
                int n = wn + j * 16 + l15;
                u16 sv[4];
#pragma unroll
                for (int e = 0; e < 4; e++) {
                    float a = acc[i][j][e];
                    a = __fadd_rn(__fmul_rn(__fsub_rn(a, mnA[e]), scA[e]), btA[e]);
                    float vv = vmem[i][j][e];
                    vv = __fadd_rn(vv, __fmul_rn(__fsub_rn(a, vv), 0.5f));
                    bool sp = (vv >= 0.5f);
                    vmem[i][j][e] = sp ? 0.0f : vv;
                    sv[e] = sp ? SPIKE_B : (u16)0;
                }
                ushort4 s4;
                s4.x = sv[0]; s4.y = sv[1]; s4.z = sv[2]; s4.w = sv[3];
                *(ushort4*)(dstp + (rb + n) * 384 + o0 + co) = s4;
            }
        }
    }
}

// ---------------------------------------------------------------------------
// K3: kv[t,b,c] = sum_n k*v. 16B loads, 8 ch/thread, LDS pre-reduce.
// grid (nc=16, tb=32), 384 thr: tid = rr*48 + c8.
// ---------------------------------------------------------------------------
__global__ void kvred_kernel(const u16* __restrict__ ks, const u16* __restrict__ vs,
                             float* __restrict__ r) {
    __shared__ float red[384];
    int tb = blockIdx.y, nc = blockIdx.x;
    int tid = threadIdx.x;
    int rr = tid / 48, c8 = tid % 48;
    red[tid] = 0.0f;
    __syncthreads();

    float cnt[8];
#pragma unroll
    for (int e = 0; e < 8; e++) cnt[e] = 0.0f;

    size_t base = ((size_t)(tb * 1024 + nc * 64 + rr)) * 384 + c8 * 8;
#pragma unroll 2
    for (int it = 0; it < 8; it++) {
        size_t off = base + (size_t)it * 8 * 384;
        uint4 ka = *(const uint4*)(ks + off);
        uint4 va = *(const uint4*)(vs + off);
        uint32_t w0 = ka.x & va.x, w1 = ka.y & va.y, w2 = ka.z & va.z, w3 = ka.w & va.w;
        const uint32_t S = SPIKE_B;
        if ((w0 & 0xFFFFu) == S) cnt[0] += 1.0f;
        if ((w0 >> 16) == S)     cnt[1] += 1.0f;
        if ((w1 & 0xFFFFu) == S) cnt[2] += 1.0f;
        if ((w1 >> 16) == S)     cnt[3] += 1.0f;
        if ((w2 & 0xFFFFu) == S) cnt[4] += 1.0f;
        if ((w2 >> 16) == S)     cnt[5] += 1.0f;
        if ((w3 & 0xFFFFu) == S) cnt[6] += 1.0f;
        if ((w3 >> 16) == S)     cnt[7] += 1.0f;
    }
#pragma unroll
    for (int e = 0; e < 8; e++) atomicAdd(&red[c8 * 8 + e], cnt[e]);
    __syncthreads();
    atomicAdd(&r[tb * 384 + tid], red[tid]);
}

// K4: talking heads (8x8 fp32) + LIF over t -> kvs[t,b,c] bf16 {0,1} mask
__global__ void talking_kernel(const float* __restrict__ r, const float* __restrict__ th,
                               u16* __restrict__ kvs) {
    int id = blockIdx.x * 256 + threadIdx.x;
    if (id >= 8 * 384) return;
    int b = id / 384, c = id % 384;
    int oh = c / 48, d = c % 48;
    float v = 0.0f;
    for (int t = 0; t < 4; t++) {
        const float* rr = r + (t * 8 + b) * 384 + d;
        float s = 0.0f;
#pragma unroll
        for (int h = 0; h < 8; h++) s = __fmaf_rn(th[oh * 8 + h], rr[h * 48], s);
        v = __fadd_rn(v, __fmul_rn(__fsub_rn(s, v), 0.5f));
        bool sp = (v >= 0.5f);
        v = sp ? 0.0f : v;
        kvs[(t * 8 + b) * 384 + c] = sp ? SPIKE_B : (u16)0;
    }
}

// ---------------------------------------------------------------------------
// K5: proj conv (K=384 bf16) + fused kvs gate + bias + BN + residual.
// 128x128 tiles, dbuf LDS, counted-vmcnt pipeline. grid (nt=8, mt=3, tb=32).
// ---------------------------------------------------------------------------
__global__ __launch_bounds__(256, 2) void proj_kernel(
    const u16* __restrict__ Aproj, const u16* __restrict__ qs, const u16* __restrict__ kvs,
    const float* __restrict__ xin,
    const float* __restrict__ pb, const float* __restrict__ pg, const float* __restrict__ pbe,
    const float* __restrict__ pm, const float* __restrict__ pv, float* __restrict__ out) {
    __shared__ __align__(16) u16 At[2][8192];
    __shared__ __align__(16) u16 Bt[2][8192];

    int tb = blockIdx.z, mt = blockIdx.y, nt = blockIdx.x;
    int m0 = mt * 128, n0 = nt * 128;
    int tid = threadIdx.x, wave = tid >> 6, lane = tid & 63;
    int l15 = lane & 15, quad = lane >> 4;
    int wm = (wave & 1) * 64, wn = (wave >> 1) * 64;

    const u16* Bsrc = qs + ((size_t)(tb * 1024 + n0)) * 384;
    const u16* mbase = kvs + tb * 384;

    auto stage = [&](int s) {
        int kk = s * 64;
        int buf = s & 1;
#pragma unroll
        for (int ii = 0; ii < 4; ii++) {
            int l = ii * 256 + tid;
            int row = l >> 3;
            int cs = (l & 7) ^ (row & 7);
            async16(Aproj + (size_t)(m0 + row) * 384 + kk + cs * 8, &At[buf][l * 8]);
            async16(Bsrc + (size_t)row * 384 + kk + cs * 8, &Bt[buf][l * 8]);
        }
    };

    f32x4 acc[4][4];
#pragma unroll
    for (int i = 0; i < 4; i++)
#pragma unroll
        for (int j = 0; j < 4; j++) acc[i][j] = (f32x4){0.f, 0.f, 0.f, 0.f};

    stage(0);
    stage(1);

#pragma unroll 1
    for (int kkb = 0; kkb < 6; kkb++) {
        int buf = kkb & 1;
        int kk = kkb * 64;
        if (kkb < 5) asm volatile("s_waitcnt vmcnt(8)\n\ts_barrier" ::: "memory");
        else         asm volatile("s_waitcnt vmcnt(0)\n\ts_barrier" ::: "memory");

#pragma unroll
        for (int h = 0; h < 2; h++) {
            int g = h * 4 + quad;
            short8v msk = *(const short8v*)(mbase + kk + g * 8);
            short8v af[4], bfr[4];
#pragma unroll
            for (int i = 0; i < 4; i++) {
                int row = wm + i * 16 + l15;
                int ch = g ^ (row & 7);
                af[i] = *(const short8v*)&At[buf][row * 64 + ch * 8];
            }
#pragma unroll
            for (int j = 0; j < 4; j++) {
                int nr = wn + j * 16 + l15;
                int ch = g ^ (nr & 7);
                bfr[j] = *(const short8v*)&Bt[buf][nr * 64 + ch * 8] & msk;  // gate
            }
            __builtin_amdgcn_s_setprio(1);
#pragma unroll
            for (int i = 0; i < 4; i++)
#pragma unroll
                for (int j = 0; j < 4; j++) acc[i][j] = mfma_bf16(af[i], bfr[j], acc[i][j]);
            __builtin_amdgcn_s_setprio(0);
        }

        asm volatile("s_waitcnt lgkmcnt(0)\n\ts_barrier" ::: "memory");
        if (kkb + 2 < 6) stage(kkb + 2);
    }

    // epilogue: y = conv+bias; (y-mean)*scale+beta; + identity (numpy order)
#pragma unroll
    for (int i = 0; i < 4; i++) {
#pragma unroll
        for (int e = 0; e < 4; e++) {
            int o = m0 + wm + i * 16 + quad * 4 + e;
            float scale = pg[o] / sqrtf(pv[o] + 1e-5f);
            float mean = pm[o], beta = pbe[o], bias = pb[o];
#pragma unroll
            for (int j = 0; j < 4; j++) {
                int n = n0 + wn + j * 16 + l15;
                size_t idx = ((size_t)tb * 384 + o) * 1024 + n;
                float y = __fadd_rn(acc[i][j][e], bias);
                y = __fadd_rn(__fmul_rn(__fsub_rn(y, mean), scale), beta);
                out[idx] = __fadd_rn(y, xin[idx]);
            }
        }
    }
}

// ---------------------------------------------------------------------------
extern "C" void kernel_launch(void* const* d_in, const int* in_sizes, int n_in,
                              void* d_out, int out_size, void* d_ws, size_t ws_size,
                              hipStream_t stream) {
    (void)in_sizes; (void)n_in; (void)out_size; (void)ws_size;
    const float* x  = (const float*)d_in[0];
    const float* qw = (const float*)d_in[1];
    const float* kw = (const float*)d_in[2];
    const float* vw = (const float*)d_in[3];
    const float* th = (const float*)d_in[4];
    const float* pw = (const float*)d_in[5];
    const float* pb = (const float*)d_in[6];
    const float* qg = (const float*)d_in[7],  *qbe = (const float*)d_in[8];
    const float* qm = (const float*)d_in[9],  *qv  = (const float*)d_in[10];
    const float* kg = (const float*)d_in[11], *kbe = (const float*)d_in[12];
    const float* km = (const float*)d_in[13], *kv_ = (const float*)d_in[14];
    const float* vg = (const float*)d_in[15], *vbe = (const float*)d_in[16];
    const float* vm = (const float*)d_in[17], *vv_ = (const float*)d_in[18];
    const float* pg = (const float*)d_in[19], *pbe = (const float*)d_in[20];
    const float* pm = (const float*)d_in[21], *pv  = (const float*)d_in[22];
    float* out = (float*)d_out;

    char* w = (char*)d_ws;
    const size_t SPIKES = (size_t)32 * 1024 * 384 * 2;  // 25,165,824 B each
    u16* xs    = (u16*)(w);
    u16* qs    = (u16*)(w + SPIKES);
    u16* ks    = (u16*)(w + 2 * SPIKES);
    u16* vs    = (u16*)(w + 3 * SPIKES);
    u16* Ah    = (u16*)(w + 4 * SPIKES);                         // 1,769,472 B
    u16* Aproj = (u16*)(w + 4 * SPIKES + 1769472);               //   294,912 B
    float* r   = (float*)(w + 4 * SPIKES + 1769472 + 294912);    //    49,152 B
    u16* kvs   = (u16*)(w + 4 * SPIKES + 1769472 + 294912 + 49152);  // 24,576 B

    hipMemsetAsync(r, 0, 32 * 384 * sizeof(float), stream);

    prep_kernel<<<1728, 256, 0, stream>>>(qw, kw, vw, pw, Ah, Aproj);
    lifx_kernel<<<dim3(16, 6, 8), 256, 0, stream>>>(x, xs);
    qkv_kernel<<<dim3(8, 9, 8), 256, 0, stream>>>(Ah, xs, qs, ks, vs,
                                                  qg, qbe, qm, qv,
                                                  kg, kbe, km, kv_,
                                                  vg, vbe, vm, vv_);
    kvred_kernel<<<dim3(16, 32), 384, 0, stream>>>(ks, vs, r);
    talking_kernel<<<12, 256, 0, stream>>>(r, th, kvs);
    proj_kernel<<<dim3(8, 3, 32), 256, 0, stream>>>(Aproj, qs, kvs, x, pb, pg, pbe, pm, pv, out);
}

// Round 3
// 264.179 us; speedup vs baseline: 3.5701x; 1.1139x over previous
//
#include <hip/hip_runtime.h>
#include <stdint.h>

// ---------------------------------------------------------------------------
// MS_SSA_Conv: spiking self-attention. T=4 B=8 C=384 N=1024 heads=8.
// R6: qkv rebuilt on the 8-wave 256x256-tile 4-phase schedule (m201-style):
//  * tile = 256 o x 256 cols (4t x 64n interleaved -> LIF over t in epilogue
//    from acc), BK=64, 12 K-tiles, dbuf LDS (128KB, 1 block/CU).
//  * per K-tile 4 phases: {ds_read subtile, stage half-tile prefetch,
//    16 MFMA in setprio(1), s_barrier}. vmcnt(0) only at q3, >=2 phases
//    after the last stage issue (latency hidden under MFMA).
//  * B-frags (k-half) reused across the two row-half phases: 24 ds_read
//    per K-tile instead of 32.
//  * M padded to 1280 (prep zeros rows 1152..1279); per-row branch/BN/dst
//    via LDS tables; qs/ks/vs addressed from one base pointer.
//  * R4 lessons kept: launch_bounds(512,2) (VGPR cap 256, no spill trap),
//    128-B LDS rows with the verified chunk^(row&7) swizzle (0 conflicts).
// ---------------------------------------------------------------------------

typedef unsigned short u16;
typedef __attribute__((ext_vector_type(8))) short short8v;
typedef __attribute__((ext_vector_type(4))) float f32x4;

#define AS1 __attribute__((address_space(1)))
#define AS3 __attribute__((address_space(3)))

__device__ __forceinline__ void async16(const void* g, void* l) {
    __builtin_amdgcn_global_load_lds((const AS1 unsigned int*)g,
                                     (AS3 unsigned int*)l, 16, 0, 0);
}
__device__ __forceinline__ f32x4 mfma_bf16(short8v a, short8v b, f32x4 c) {
    return __builtin_amdgcn_mfma_f32_16x16x32_bf16(a, b, c, 0, 0, 0);
}
__device__ __forceinline__ f32x4 mfma_f16(short8v a, short8v b, f32x4 c) {
    return __builtin_amdgcn_mfma_f32_16x16x32_f16(a, b, c, 0, 0, 0);
}

__device__ __forceinline__ u16 f2bf(float f) {  // RNE fp32->bf16
    uint32_t x = __float_as_uint(f);
    return (u16)((x + 0x7FFFu + ((x >> 16) & 1u)) >> 16);
}

#define SPIKE_H ((u16)0x3C00)  // fp16 1.0 (xs)
#define SPIKE_B ((u16)0x3F80)  // bf16 1.0 (q/k/v spikes, kvs mask)

// ---------------------------------------------------------------------------
// K0: weights. Ah [1280][768] fp16 2-part split (rows 1152.. zero-padded);
// Aproj [384][384] bf16.
// ---------------------------------------------------------------------------
__global__ void prep_kernel(const float* __restrict__ qw, const float* __restrict__ kw,
                            const float* __restrict__ vw, const float* __restrict__ pw,
                            u16* __restrict__ Ah, u16* __restrict__ Aproj) {
    int id = blockIdx.x * 256 + threadIdx.x;
    if (id >= 1280 * 384) return;
    int m = id / 384, c = id % 384;
    u16* row = Ah + (size_t)m * 768;
    if (m >= 1152) { row[c] = 0; row[384 + c] = 0; return; }
    int br = m / 384, o = m % 384;
    const float* W = (br == 0) ? qw : (br == 1) ? kw : vw;
    float w = W[o * 384 + c];
    union H { _Float16 h; u16 u; } u0, u1;
    u0.h = (_Float16)w;
    float r1 = w - (float)u0.h;
    u1.h = (_Float16)r1;
    row[c] = u0.u;
    row[384 + c] = u1.u;
    if (br == 0) Aproj[o * 384 + c] = f2bf(pw[o * 384 + c]);
}

// ---------------------------------------------------------------------------
// K1: shortcut LIF on x -> xs[t,b,n,c] fp16 spikes.
// ---------------------------------------------------------------------------
__global__ __launch_bounds__(256) void lifx_kernel(const float* __restrict__ x,
                                                   u16* __restrict__ xs) {
    __shared__ u16 Tr[64 * 72];
    int b = blockIdx.z, c0 = blockIdx.y * 64, n0 = blockIdx.x * 64;
    int tid = threadIdx.x;
    int nj = (tid & 15) * 4;
    int ci = tid >> 4;
    float v[4][4];
#pragma unroll
    for (int p = 0; p < 4; p++)
#pragma unroll
        for (int e = 0; e < 4; e++) v[p][e] = 0.0f;

    for (int t = 0; t < 4; t++) {
#pragma unroll
        for (int p = 0; p < 4; p++) {
            const float* src = x + ((size_t)((t * 8 + b) * 384 + c0 + p * 16 + ci)) * 1024 + n0 + nj;
            float4 xv = *(const float4*)src;
            float xa[4] = {xv.x, xv.y, xv.z, xv.w};
#pragma unroll
            for (int e = 0; e < 4; e++) {
                float vv = v[p][e];
                vv = __fadd_rn(vv, __fmul_rn(__fsub_rn(xa[e], vv), 0.5f));
                bool sp = (vv >= 0.5f);
                v[p][e] = sp ? 0.0f : vv;
                Tr[(nj + e) * 72 + p * 16 + ci] = sp ? SPIKE_H : (u16)0;
            }
        }
        __syncthreads();
#pragma unroll
        for (int p = 0; p < 4; p++) {
            int nr = p * 16 + (tid >> 4);
            int c4 = (tid & 15) * 4;
            *(ushort4*)(xs + ((size_t)((t * 8 + b) * 1024 + n0 + nr)) * 384 + c0 + c4) =
                *(const ushort4*)&Tr[nr * 72 + c4];
        }
        __syncthreads();
    }
}

// ---------------------------------------------------------------------------
// K2: QKV conv (2-part fp16, K=768) + BN + LIF over t (from acc, epilogue).
// Tile 256 o x 256 col (col = wn4*64 + t*16 + l15 -> 4t x 64n), BK=64,
// 12 K-tiles x 4 phases. 8 waves: wmh = wave>>2 (row half), wn4 = wave&3.
// grid (nt=16, mt=5, b=8), 512 threads.
// ---------------------------------------------------------------------------
__global__ __launch_bounds__(512, 2) void qkv_kernel(
    const u16* __restrict__ Ah, const u16* __restrict__ xs, u16* __restrict__ qs,
    const float* __restrict__ qg, const float* __restrict__ qb, const float* __restrict__ qm, const float* __restrict__ qv,
    const float* __restrict__ kg, const float* __restrict__ kb, const float* __restrict__ km, const float* __restrict__ kvr,
    const float* __restrict__ vg, const float* __restrict__ vb, const float* __restrict__ vm, const float* __restrict__ vvr) {
    __shared__ __align__(16) u16 At[2][2][8192];  // [buf][rowhalf][128*64]
    __shared__ __align__(16) u16 Bt[2][2][8192];  // [buf][colhalf][128*64]
    __shared__ float bnS[256], bnM[256], bnB[256];
    __shared__ int roff[256];

    const int b = blockIdx.z, mt = blockIdx.y, nt = blockIdx.x;
    const int m0 = mt * 256, n0 = nt * 64;
    const int tid = threadIdx.x, wave = tid >> 6, lane = tid & 63;
    const int l15 = lane & 15, quad = lane >> 4;
    const int wmh = wave >> 2;        // 0/1: row half (128 rows)
    const int wn4 = wave & 3;         // 0..3: 64-col group
    const int bh = wn4 >> 1;          // B half
    const int cb = (wn4 & 1) * 64;    // col base within B half

    // per-row BN params + dst offset table (branch folded into offset:
    // qs/ks/vs are contiguous, 12582912 u16 apart)
    if (tid < 256) {
        int g = m0 + tid;
        if (g < 1152) {
            int br = g / 384, o = g - br * 384;
            const float* gp = (br == 0) ? qg : (br == 1) ? kg : vg;
            const float* bp = (br == 0) ? qb : (br == 1) ? kb : vb;
            const float* mp = (br == 0) ? qm : (br == 1) ? km : vm;
            const float* vp = (br == 0) ? qv : (br == 1) ? kvr : vvr;
            bnS[tid] = gp[o] / sqrtf(vp[o] + 1e-5f);
            bnM[tid] = mp[o];
            bnB[tid] = bp[o];
            roff[tid] = br * 12582912 + o;
        } else {
            bnS[tid] = 0.f; bnM[tid] = 0.f; bnB[tid] = 0.f; roff[tid] = 0;
        }
    }

    // staging geometry: load l = d*512 + tid covers (row/col = d*64 + (tid>>3),
    // chunk = tid&7), source chunk pre-swizzled (involution with read side)
    const int cl = tid >> 3;                       // 0..63
    const int cs8 = ((tid & 7) ^ (cl & 7)) * 8;    // swizzled chunk (u16)
    const int dst0 = tid * 8;                      // linear LDS dest (u16)

    const u16* pA = Ah + (size_t)(m0 + cl) * 768 + cs8;
    auto mkB = [&](int C) {  // tile col C -> xs address (t,n interleave)
        int t = (C >> 4) & 3;
        int nl = (C >> 6) * 16 + (C & 15);
        return xs + ((size_t)((t * 8 + b) * 1024 + n0 + nl)) * 384 + cs8;
    };
    const u16* pB00 = mkB(cl);        // B half 0, ld 0
    const u16* pB01 = mkB(64 + cl);   // B half 0, ld 1
    const u16* pB10 = mkB(128 + cl);  // B half 1, ld 0
    const u16* pB11 = mkB(192 + cl);  // B half 1, ld 1

    auto stA0 = [&](int Tn) { int buf = Tn & 1, kk = Tn * 64;
        async16(pA + kk,          &At[buf][0][dst0]);
        async16(pA + 49152 + kk,  &At[buf][0][4096 + dst0]); };
    auto stA1 = [&](int Tn) { int buf = Tn & 1, kk = Tn * 64;
        async16(pA + 98304 + kk,          &At[buf][1][dst0]);
        async16(pA + 98304 + 49152 + kk,  &At[buf][1][4096 + dst0]); };
    auto stB0 = [&](int Tn) { int buf = Tn & 1, kk = Tn * 64;
        int ck = (kk >= 384) ? kk - 384 : kk;  // 2-part split: B repeats
        async16(pB00 + ck, &Bt[buf][0][dst0]);
        async16(pB01 + ck, &Bt[buf][0][4096 + dst0]); };
    auto stB1 = [&](int Tn) { int buf = Tn & 1, kk = Tn * 64;
        int ck = (kk >= 384) ? kk - 384 : kk;
        async16(pB10 + ck, &Bt[buf][1][dst0]);
        async16(pB11 + ck, &Bt[buf][1][4096 + dst0]); };

    // fragment read constants (swizzled chunk: (k-group)^(row&7), row&7==l15&7)
    const int ch0 = (quad ^ (l15 & 7)) * 8;        // kk2 = 0
    const int ch1 = ((4 + quad) ^ (l15 & 7)) * 8;  // kk2 = 1
    const int abase = l15 * 64;

    f32x4 acc[8][4];
#pragma unroll
    for (int i = 0; i < 8; i++)
#pragma unroll
        for (int j = 0; j < 4; j++) acc[i][j] = (f32x4){0.f, 0.f, 0.f, 0.f};

    short8v af[4], bf[4];

#define LOAD_A(BUF, QH, CH) { const u16* Ap = &At[BUF][wmh][(QH)*4096 + abase + (CH)]; \
    af[0] = *(const short8v*)Ap;          af[1] = *(const short8v*)(Ap + 1024); \
    af[2] = *(const short8v*)(Ap + 2048); af[3] = *(const short8v*)(Ap + 3072); }
#define LOAD_B(BUF, CH) { const u16* Bp = &Bt[BUF][bh][cb*64 + abase + (CH)]; \
    bf[0] = *(const short8v*)Bp;          bf[1] = *(const short8v*)(Bp + 1024); \
    bf[2] = *(const short8v*)(Bp + 2048); bf[3] = *(const short8v*)(Bp + 3072); }
#define MFMA16(QH) { __builtin_amdgcn_s_setprio(1); \
    _Pragma("unroll") for (int i = 0; i < 4; i++) \
    _Pragma("unroll") for (int j = 0; j < 4; j++) \
        acc[(QH)*4 + i][j] = mfma_f16(af[i], bf[j], acc[(QH)*4 + i][j]); \
    __builtin_amdgcn_s_setprio(0); }

    // prologue: stage tile 0, full drain once
    stA0(0); stB0(0); stA1(0); stB1(0);
    __syncthreads();

#pragma unroll 1
    for (int T = 0; T < 12; T++) {
        int buf = T & 1;
        bool pf = (T < 11);
        // q0: (rowhalf 0, k-half 0); stage A0+B0 of T+1
        LOAD_A(buf, 0, ch0)
        LOAD_B(buf, ch0)
        if (pf) { stA0(T + 1); stB0(T + 1); }
        MFMA16(0)
        asm volatile("s_barrier" ::: "memory");
        // q1: (rowhalf 1, k-half 0) -- reuse bf; stage A1+B1 of T+1
        LOAD_A(buf, 1, ch0)
        if (pf) { stA1(T + 1); stB1(T + 1); }
        MFMA16(1)
        asm volatile("s_barrier" ::: "memory");
        // q2: (rowhalf 0, k-half 1)
        LOAD_A(buf, 0, ch1)
        LOAD_B(buf, ch1)
        MFMA16(0)
        asm volatile("s_barrier" ::: "memory");
        // q3: (rowhalf 1, k-half 1); drain (issued >=2 phases ago) + publish
        LOAD_A(buf, 1, ch1)
        MFMA16(1)
        asm volatile("s_waitcnt vmcnt(0)\n\ts_barrier" ::: "memory");
    }
#undef LOAD_A
#undef LOAD_B
#undef MFMA16

    // epilogue: BN + LIF over t (exact numpy order) from accumulators
    const int nn = n0 + wn4 * 16 + l15;
#pragma unroll
    for (int mi = 0; mi < 8; mi++) {
        int rbw = wmh * 128 + (mi >> 2) * 64 + (mi & 3) * 16;  // wave-uniform
        if (m0 + rbw >= 1152) continue;                        // padded rows
        int rbase = rbw + quad * 4;
        float4 s4 = *(const float4*)&bnS[rbase];
        float4 m4 = *(const float4*)&bnM[rbase];
        float4 b4 = *(const float4*)&bnB[rbase];
        float sc[4] = {s4.x, s4.y, s4.z, s4.w};
        float mn[4] = {m4.x, m4.y, m4.z, m4.w};
        float bt[4] = {b4.x, b4.y, b4.z, b4.w};
        int ro = roff[rbase];
        u16 sv[4][4];  // [t][e]
#pragma unroll
        for (int e = 0; e < 4; e++) {
            float vv = 0.0f;
#pragma unroll
            for (int t = 0; t < 4; t++) {
                float a = acc[mi][t][e];
                a = __fadd_rn(__fmul_rn(__fsub_rn(a, mn[e]), sc[e]), bt[e]);
                vv = __fadd_rn(vv, __fmul_rn(__fsub_rn(a, vv), 0.5f));
                bool sp = (vv >= 0.5f);
                vv = sp ? 0.0f : vv;
                sv[t][e] = sp ? SPIKE_B : (u16)0;
            }
        }
#pragma unroll
        for (int t = 0; t < 4; t++) {
            ushort4 o4;
            o4.x = sv[t][0]; o4.y = sv[t][1]; o4.z = sv[t][2]; o4.w = sv[t][3];
            *(ushort4*)(qs + (size_t)ro + ((size_t)((t * 8 + b) * 1024 + nn)) * 384) = o4;
        }
    }
}

// ---------------------------------------------------------------------------
// K3: kv[t,b,c] = sum_n k*v. 16B loads, 8 ch/thread, LDS pre-reduce.
// grid (nc=16, tb=32), 384 thr: tid = rr*48 + c8.
// ---------------------------------------------------------------------------
__global__ void kvred_kernel(const u16* __restrict__ ks, const u16* __restrict__ vs,
                             float* __restrict__ r) {
    __shared__ float red[384];
    int tb = blockIdx.y, nc = blockIdx.x;
    int tid = threadIdx.x;
    int rr = tid / 48, c8 = tid % 48;
    red[tid] = 0.0f;
    __syncthreads();

    float cnt[8];
#pragma unroll
    for (int e = 0; e < 8; e++) cnt[e] = 0.0f;

    size_t base = ((size_t)(tb * 1024 + nc * 64 + rr)) * 384 + c8 * 8;
#pragma unroll 2
    for (int it = 0; it < 8; it++) {
        size_t off = base + (size_t)it * 8 * 384;
        uint4 ka = *(const uint4*)(ks + off);
        uint4 va = *(const uint4*)(vs + off);
        uint32_t w0 = ka.x & va.x, w1 = ka.y & va.y, w2 = ka.z & va.z, w3 = ka.w & va.w;
        const uint32_t S = SPIKE_B;
        if ((w0 & 0xFFFFu) == S) cnt[0] += 1.0f;
        if ((w0 >> 16) == S)     cnt[1] += 1.0f;
        if ((w1 & 0xFFFFu) == S) cnt[2] += 1.0f;
        if ((w1 >> 16) == S)     cnt[3] += 1.0f;
        if ((w2 & 0xFFFFu) == S) cnt[4] += 1.0f;
        if ((w2 >> 16) == S)     cnt[5] += 1.0f;
        if ((w3 & 0xFFFFu) == S) cnt[6] += 1.0f;
        if ((w3 >> 16) == S)     cnt[7] += 1.0f;
    }
#pragma unroll
    for (int e = 0; e < 8; e++) atomicAdd(&red[c8 * 8 + e], cnt[e]);
    __syncthreads();
    atomicAdd(&r[tb * 384 + tid], red[tid]);
}

// K4: talking heads (8x8 fp32) + LIF over t -> kvs[t,b,c] bf16 {0,1} mask
__global__ void talking_kernel(const float* __restrict__ r, const float* __restrict__ th,
                               u16* __restrict__ kvs) {
    int id = blockIdx.x * 256 + threadIdx.x;
    if (id >= 8 * 384) return;
    int b = id / 384, c = id % 384;
    int oh = c / 48, d = c % 48;
    float v = 0.0f;
    for (int t = 0; t < 4; t++) {
        const float* rr = r + (t * 8 + b) * 384 + d;
        float s = 0.0f;
#pragma unroll
        for (int h = 0; h < 8; h++) s = __fmaf_rn(th[oh * 8 + h], rr[h * 48], s);
        v = __fadd_rn(v, __fmul_rn(__fsub_rn(s, v), 0.5f));
        bool sp = (v >= 0.5f);
        v = sp ? 0.0f : v;
        kvs[(t * 8 + b) * 384 + c] = sp ? SPIKE_B : (u16)0;
    }
}

// ---------------------------------------------------------------------------
// K5: proj conv (K=384 bf16) + fused kvs gate + bias + BN + residual.
// 128x128 tiles, dbuf LDS, counted-vmcnt pipeline. grid (nt=8, mt=3, tb=32).
// ---------------------------------------------------------------------------
__global__ __launch_bounds__(256, 2) void proj_kernel(
    const u16* __restrict__ Aproj, const u16* __restrict__ qs, const u16* __restrict__ kvs,
    const float* __restrict__ xin,
    const float* __restrict__ pb, const float* __restrict__ pg, const float* __restrict__ pbe,
    const float* __restrict__ pm, const float* __restrict__ pv, float* __restrict__ out) {
    __shared__ __align__(16) u16 At[2][8192];
    __shared__ __align__(16) u16 Bt[2][8192];

    int tb = blockIdx.z, mt = blockIdx.y, nt = blockIdx.x;
    int m0 = mt * 128, n0 = nt * 128;
    int tid = threadIdx.x, wave = tid >> 6, lane = tid & 63;
    int l15 = lane & 15, quad = lane >> 4;
    int wm = (wave & 1) * 64, wn = (wave >> 1) * 64;

    const u16* Bsrc = qs + ((size_t)(tb * 1024 + n0)) * 384;
    const u16* mbase = kvs + tb * 384;

    auto stage = [&](int s) {
        int kk = s * 64;
        int buf = s & 1;
#pragma unroll
        for (int ii = 0; ii < 4; ii++) {
            int l = ii * 256 + tid;
            int row = l >> 3;
            int cs = (l & 7) ^ (row & 7);
            async16(Aproj + (size_t)(m0 + row) * 384 + kk + cs * 8, &At[buf][l * 8]);
            async16(Bsrc + (size_t)row * 384 + kk + cs * 8, &Bt[buf][l * 8]);
        }
    };

    f32x4 acc[4][4];
#pragma unroll
    for (int i = 0; i < 4; i++)
#pragma unroll
        for (int j = 0; j < 4; j++) acc[i][j] = (f32x4){0.f, 0.f, 0.f, 0.f};

    stage(0);
    stage(1);

#pragma unroll 1
    for (int kkb = 0; kkb < 6; kkb++) {
        int buf = kkb & 1;
        int kk = kkb * 64;
        if (kkb < 5) asm volatile("s_waitcnt vmcnt(8)\n\ts_barrier" ::: "memory");
        else         asm volatile("s_waitcnt vmcnt(0)\n\ts_barrier" ::: "memory");

#pragma unroll
        for (int h = 0; h < 2; h++) {
            int g = h * 4 + quad;
            short8v msk = *(const short8v*)(mbase + kk + g * 8);
            short8v af[4], bfr[4];
#pragma unroll
            for (int i = 0; i < 4; i++) {
                int row = wm + i * 16 + l15;
                int ch = g ^ (row & 7);
                af[i] = *(const short8v*)&At[buf][row * 64 + ch * 8];
            }
#pragma unroll
            for (int j = 0; j < 4; j++) {
                int nr = wn + j * 16 + l15;
                int ch = g ^ (nr & 7);
                bfr[j] = *(const short8v*)&Bt[buf][nr * 64 + ch * 8] & msk;  // gate
            }
            __builtin_amdgcn_s_setprio(1);
#pragma unroll
            for (int i = 0; i < 4; i++)
#pragma unroll
                for (int j = 0; j < 4; j++) acc[i][j] = mfma_bf16(af[i], bfr[j], acc[i][j]);
            __builtin_amdgcn_s_setprio(0);
        }

        asm volatile("s_waitcnt lgkmcnt(0)\n\ts_barrier" ::: "memory");
        if (kkb + 2 < 6) stage(kkb + 2);
    }

    // epilogue: y = conv+bias; (y-mean)*scale+beta; + identity (numpy order)
#pragma unroll
    for (int i = 0; i < 4; i++) {
#pragma unroll
        for (int e = 0; e < 4; e++) {
            int o = m0 + wm + i * 16 + quad * 4 + e;
            float scale = pg[o] / sqrtf(pv[o] + 1e-5f);
            float mean = pm[o], beta = pbe[o], bias = pb[o];
#pragma unroll
            for (int j = 0; j < 4; j++) {
                int n = n0 + wn + j * 16 + l15;
                size_t idx = ((size_t)tb * 384 + o) * 1024 + n;
                float y = __fadd_rn(acc[i][j][e], bias);
                y = __fadd_rn(__fmul_rn(__fsub_rn(y, mean), scale), beta);
                out[idx] = __fadd_rn(y, xin[idx]);
            }
        }
    }
}

// ---------------------------------------------------------------------------
extern "C" void kernel_launch(void* const* d_in, const int* in_sizes, int n_in,
                              void* d_out, int out_size, void* d_ws, size_t ws_size,
                              hipStream_t stream) {
    (void)in_sizes; (void)n_in; (void)out_size; (void)ws_size;
    const float* x  = (const float*)d_in[0];
    const float* qw = (const float*)d_in[1];
    const float* kw = (const float*)d_in[2];
    const float* vw = (const float*)d_in[3];
    const float* th = (const float*)d_in[4];
    const float* pw = (const float*)d_in[5];
    const float* pb = (const float*)d_in[6];
    const float* qg = (const float*)d_in[7],  *qbe = (const float*)d_in[8];
    const float* qm = (const float*)d_in[9],  *qv  = (const float*)d_in[10];
    const float* kg = (const float*)d_in[11], *kbe = (const float*)d_in[12];
    const float* km = (const float*)d_in[13], *kv_ = (const float*)d_in[14];
    const float* vg = (const float*)d_in[15], *vbe = (const float*)d_in[16];
    const float* vm = (const float*)d_in[17], *vv_ = (const float*)d_in[18];
    const float* pg = (const float*)d_in[19], *pbe = (const float*)d_in[20];
    const float* pm = (const float*)d_in[21], *pv  = (const float*)d_in[22];
    float* out = (float*)d_out;

    char* w = (char*)d_ws;
    const size_t SPIKES = (size_t)32 * 1024 * 384 * 2;  // 25,165,824 B each
    u16* xs    = (u16*)(w);
    u16* qs    = (u16*)(w + SPIKES);
    u16* ks    = (u16*)(w + 2 * SPIKES);
    u16* vs    = (u16*)(w + 3 * SPIKES);
    u16* Ah    = (u16*)(w + 4 * SPIKES);                         // 1,966,080 B
    u16* Aproj = (u16*)(w + 4 * SPIKES + 1966080);               //   294,912 B
    float* r   = (float*)(w + 4 * SPIKES + 1966080 + 294912);    //    49,152 B
    u16* kvs   = (u16*)(w + 4 * SPIKES + 1966080 + 294912 + 49152);  // 24,576 B

    hipMemsetAsync(r, 0, 32 * 384 * sizeof(float), stream);

    prep_kernel<<<1920, 256, 0, stream>>>(qw, kw, vw, pw, Ah, Aproj);
    lifx_kernel<<<dim3(16, 6, 8), 256, 0, stream>>>(x, xs);
    qkv_kernel<<<dim3(16, 5, 8), 512, 0, stream>>>(Ah, xs, qs,
                                                   qg, qbe, qm, qv,
                                                   kg, kbe, km, kv_,
                                                   vg, vbe, vm, vv_);
    kvred_kernel<<<dim3(16, 32), 384, 0, stream>>>(ks, vs, r);
    talking_kernel<<<12, 256, 0, stream>>>(r, th, kvs);
    proj_kernel<<<dim3(8, 3, 32), 256, 0, stream>>>(Aproj, qs, kvs, x, pb, pg, pbe, pm, pv, out);
}